// Round 6
// baseline (907.884 us; speedup 1.0000x reference)
//
#include <hip/hip_runtime.h>
#include <hip/hip_bf16.h>

typedef __attribute__((ext_vector_type(4))) float f32x4;
typedef __attribute__((ext_vector_type(8))) short short8;

#define DEVI __device__ __forceinline__

DEVI unsigned short f2bf(float x) {
  union { float f; unsigned u; } v; v.f = x;
  unsigned r = v.u + 0x7fffu + ((v.u >> 16) & 1u);
  return (unsigned short)(r >> 16);
}
DEVI float bf2f(unsigned short h) {
  union { unsigned u; float f; } v; v.u = ((unsigned)h) << 16;
  return v.f;
}
DEVI short8 pack8(f32x4 lo, f32x4 hi) {
  short8 r;
  r[0] = (short)f2bf(lo[0]); r[1] = (short)f2bf(lo[1]);
  r[2] = (short)f2bf(lo[2]); r[3] = (short)f2bf(lo[3]);
  r[4] = (short)f2bf(hi[0]); r[5] = (short)f2bf(hi[1]);
  r[6] = (short)f2bf(hi[2]); r[7] = (short)f2bf(hi[3]);
  return r;
}

DEVI void gld16(const void* g, void* l) {
  __builtin_amdgcn_global_load_lds(
      (const __attribute__((address_space(1))) void*)g,
      (__attribute__((address_space(3))) void*)l, 16, 0, 0);
}

// ---------- prep: fp32 -> bf16 for W_hh0, W_hh1, W_ih1, W_ih0 ----------
__global__ __launch_bounds__(256) void prep_cvt(
    const float* __restrict__ whh0, const float* __restrict__ whh1,
    const float* __restrict__ wih1, const float* __restrict__ wih0,
    short* __restrict__ o_whh0, short* __restrict__ o_whh1,
    short* __restrict__ o_wih1, short* __restrict__ o_wih0) {
  int i = blockIdx.x * 256 + threadIdx.x;
  if (i < 262144) { o_whh0[i] = (short)f2bf(whh0[i]); return; }
  if (i < 524288) { int j = i - 262144; o_whh1[j] = (short)f2bf(whh1[j]); return; }
  if (i < 786432) { int j = i - 524288; o_wih1[j] = (short)f2bf(wih1[j]); return; }
  if (i < 917504) { int j = i - 786432; o_wih0[j] = (short)f2bf(wih0[j]); return; }
}

// ---------- GEMM: pre = A @ W^T + bias_a + bias_b  (bf16 out) ----------
template<int KDIM, bool GATHER>
__global__ __launch_bounds__(256) void gemm_pre(
    const float* __restrict__ embed, const int* __restrict__ xtok,
    const short* __restrict__ Abf, const short* __restrict__ Bbf,
    const float* __restrict__ bias_a, const float* __restrict__ bias_b,
    short* __restrict__ out) {
  __shared__ short smem[16384];          // As[128][64] @0, Bs[128][64] @8192 (shorts)
  short* As = smem;
  short* Bs = smem + 8192;

  const int tid = threadIdx.x;
  const int bM = (int)blockIdx.x >> 2;
  const int bN = (int)blockIdx.x & 3;
  const int m0 = bM * 128, n0 = bN * 128;

  f32x4 acc[4][4];
#pragma unroll
  for (int i = 0; i < 4; ++i)
#pragma unroll
    for (int j = 0; j < 4; ++j) acc[i][j] = (f32x4){0.f, 0.f, 0.f, 0.f};

  const int lane = tid & 63, wid = tid >> 6;
  const int wm = wid >> 1, wn = wid & 1;
  const int l15 = lane & 15, lk = lane >> 4;

  const int srow = tid >> 1;
  const int skh = (tid & 1) * 32;
  const int sxor = (srow & 7) << 4;
  const int sbyte0 = srow * 128 + skh * 2;

  const float* aG = nullptr;
  const short* aB = nullptr;
  if (GATHER) {
    int r = m0 + srow;
    int t = r >> 11, n = r & 2047;
    int tok = xtok[(n << 5) + t];
    aG = embed + (size_t)tok * 256;
  } else {
    aB = Abf + (size_t)(m0 + srow) * KDIM;
  }
  const short* bRow = Bbf + (size_t)(n0 + srow) * KDIM;

  for (int kb = 0; kb < KDIM; kb += 64) {
    __syncthreads();
#pragma unroll
    for (int c = 0; c < 4; ++c) {
      short8 pa;
      if (GATHER) {
        const float* src = aG + kb + skh + c * 8;
        f32x4 lo = *(const f32x4*)(src);
        f32x4 hi = *(const f32x4*)(src + 4);
        pa = pack8(lo, hi);
      } else {
        pa = *(const short8*)(aB + kb + skh + c * 8);
      }
      *(short8*)((char*)As + ((sbyte0 + c * 16) ^ sxor)) = pa;
      short8 pb = *(const short8*)(bRow + kb + skh + c * 8);
      *(short8*)((char*)Bs + ((sbyte0 + c * 16) ^ sxor)) = pb;
    }
    __syncthreads();
#pragma unroll
    for (int kt = 0; kt < 2; ++kt) {
      short8 av[4], bv[4];
#pragma unroll
      for (int mi = 0; mi < 4; ++mi) {
        int row = wm * 64 + mi * 16 + l15;
        int off = (row * 128 + kt * 64 + lk * 16) ^ ((row & 7) << 4);
        av[mi] = *(const short8*)((const char*)As + off);
      }
#pragma unroll
      for (int ni = 0; ni < 4; ++ni) {
        int col = wn * 64 + ni * 16 + l15;
        int off = (col * 128 + kt * 64 + lk * 16) ^ ((col & 7) << 4);
        bv[ni] = *(const short8*)((const char*)Bs + off);
      }
#pragma unroll
      for (int mi = 0; mi < 4; ++mi)
#pragma unroll
        for (int ni = 0; ni < 4; ++ni)
          acc[mi][ni] = __builtin_amdgcn_mfma_f32_16x16x32_bf16(av[mi], bv[ni], acc[mi][ni], 0, 0, 0);
    }
  }
  __syncthreads();
  float bsum[4];
#pragma unroll
  for (int ni = 0; ni < 4; ++ni) {
    int cg = n0 + wn * 64 + ni * 16 + l15;
    bsum[ni] = bias_a[cg] + bias_b[cg];
  }
  short* Cs = smem;
#pragma unroll
  for (int mi = 0; mi < 4; ++mi)
#pragma unroll
    for (int ni = 0; ni < 4; ++ni)
#pragma unroll
      for (int r = 0; r < 4; ++r) {
        int row = wm * 64 + mi * 16 + lk * 4 + r;
        int col = wn * 64 + ni * 16 + l15;
        Cs[row * 128 + col] = (short)f2bf(acc[mi][ni][r] + bsum[ni]);
      }
  __syncthreads();
  {
    int row = tid >> 1, colh = (tid & 1) * 64;
    size_t gbase = (size_t)(m0 + row) * 512 + n0 + colh;
#pragma unroll
    for (int c = 0; c < 8; ++c)
      *(short8*)(out + gbase + c * 8) = *(const short8*)&Cs[row * 128 + colh + c * 8];
  }
}

// ---- recurrence helpers: streamed-W chunk load / consume (static kt) ----
template<int KT0>
DEVI void loadc(short8 (&buf)[2][4], const short* wbase) {
#pragma unroll
  for (int q = 0; q < 2; ++q)
#pragma unroll
    for (int ni = 0; ni < 4; ++ni)
      buf[q][ni] = *(const short8*)(wbase + ni * 8192 + (KT0 + q) * 32);
}

template<int KT0>
DEVI void consume(const short8 (&buf)[2][4], const char* abase, int lk16, int axor,
                  f32x4 (&acc)[4]) {
#pragma unroll
  for (int q = 0; q < 2; ++q) {
    short8 a = *(const short8*)(abase + (((KT0 + q) * 64 + lk16) ^ axor));
    acc[0] = __builtin_amdgcn_mfma_f32_16x16x32_bf16(a, buf[q][0], acc[0], 0, 0, 0);
    acc[1] = __builtin_amdgcn_mfma_f32_16x16x32_bf16(a, buf[q][1], acc[1], 0, 0, 0);
    acc[2] = __builtin_amdgcn_mfma_f32_16x16x32_bf16(a, buf[q][2], acc[2], 0, 0, 0);
    acc[3] = __builtin_amdgcn_mfma_f32_16x16x32_bf16(a, buf[q][3], acc[3], 0, 0, 0);
  }
}

// ---------- recurrence: h_t = relu(pre_t + h_{t-1} @ W_hh^T) ----------
// 256 blocks x 512 threads (8 waves, 1 block/CU via 152 KB LDS). Block owns
// 8 sequences; wave owns 64 output cols. W: kt 0..3 LDS-stationary (128 KB,
// loaded once, swizzled), kt 4..15 streamed L2->VGPR every step as 6 chunks
// of 2kt (32 regs), 2-buffer pipeline. Peak VGPR demand ~105 -> no spill.
template<bool WRITE_OUTS>
__global__ __launch_bounds__(512) void recur(
    const short* __restrict__ pre,   // [32][2048][512] bf16
    const short* __restrict__ Wbf,   // [512][512] bf16 (row h_out contiguous in k)
    short* __restrict__ outs,        // [32][2048][512] bf16 (WRITE_OUTS)
    float* __restrict__ hlast) {     // [2048][512] f32 (!WRITE_OUTS)
  __shared__ __align__(16) char Wl[131072];  // [8 waves][64 cols][16 chunks 16B] swizzled
  __shared__ __align__(16) char hl[16384];   // h [16 rows][512] bf16 swizzled (rows 8..15 = 0)
  __shared__ __align__(16) char plds[8192];  // pre tile [8][512] bf16 linear
  const int tid = threadIdx.x;
  const int lane = tid & 63, wid = tid >> 6;
  const int l15 = lane & 15, lk = lane >> 4;
  const int n0 = (int)blockIdx.x * 8;

  // ---- one-time: stage stationary W (k 0..127 of each owned col) into Wl ----
  // linear LDS slot s=it*64+lane holds chunk (s&15)^((s>>4)&7) of col s>>4
  // (pre-swizzled global source so the ds_read side can XOR-deswizzle).
  {
    const short* wsb = Wbf + (size_t)(wid * 64) * 512;
#pragma unroll
    for (int it = 0; it < 16; ++it) {
      int s = it * 64 + lane;
      int col_r = s >> 4, cl = s & 15;
      int cs = cl ^ (col_r & 7);
      gld16(wsb + col_r * 512 + cs * 8, Wl + wid * 16384 + it * 1024);
    }
  }
  // zero h(-1) (all 16 rows; rows 8..15 stay zero forever)
  {
    short8 z = {0, 0, 0, 0, 0, 0, 0, 0};
    *(short8*)(hl + tid * 32) = z;
    *(short8*)(hl + tid * 32 + 16) = z;
  }
  __syncthreads();

  const short* wbase = Wbf + (size_t)(wid * 64 + l15) * 512 + lk * 8;  // streamed src
  const char* abase = hl + l15 * 1024;
  const int lk16 = lk * 16;
  const int axor = (l15 & 7) << 4;
  const char* wlbase = Wl + wid * 16384;

#pragma unroll 1
  for (int t = 0; t < 32; ++t) {
    // stage pre tile (8 KB) -> plds (1 slot / thread), consumed in the epilogue
    gld16(pre + ((size_t)t * 2048 + n0) * 512 + (wid * 64 + lane) * 8,
          plds + wid * 1024);

    // stream h(t-1) row wid to outs (LDS read; precedes the barrier)
    if (WRITE_OUTS && t > 0) {
      short8 v = *(const short8*)(hl + wid * 1024 + ((lane * 16) ^ ((wid & 7) << 4)));
      *(short8*)(outs + ((size_t)(t - 1) * 2048 + n0 + wid) * 512 + lane * 8) = v;
    }

    f32x4 acc[4];
#pragma unroll
    for (int ni = 0; ni < 4; ++ni) acc[ni] = (f32x4){0.f, 0.f, 0.f, 0.f};

    short8 cA[2][4], cB[2][4];
    loadc<4>(cA, wbase);
    loadc<6>(cB, wbase);
    __builtin_amdgcn_sched_barrier(0);

    // stationary MFMAs kt 0..3 from Wl (covers the load latency of cA/cB)
#pragma unroll
    for (int kt = 0; kt < 4; ++kt) {
      short8 a = *(const short8*)(abase + ((kt * 64 + lk16) ^ axor));
#pragma unroll
      for (int ni = 0; ni < 4; ++ni) {
        int col_r = ni * 16 + l15;
        short8 b = *(const short8*)(wlbase + col_r * 256 + ((kt * 4 + lk) ^ (col_r & 7)) * 16);
        acc[ni] = __builtin_amdgcn_mfma_f32_16x16x32_bf16(a, b, acc[ni], 0, 0, 0);
      }
    }
    __builtin_amdgcn_sched_barrier(0);

    // streamed pipeline: consume chunk, immediately re-load its buffer
    consume<4>(cA, abase, lk16, axor, acc);
    __builtin_amdgcn_sched_barrier(0);
    loadc<8>(cA, wbase);
    __builtin_amdgcn_sched_barrier(0);
    consume<6>(cB, abase, lk16, axor, acc);
    __builtin_amdgcn_sched_barrier(0);
    loadc<10>(cB, wbase);
    __builtin_amdgcn_sched_barrier(0);
    consume<8>(cA, abase, lk16, axor, acc);
    __builtin_amdgcn_sched_barrier(0);
    loadc<12>(cA, wbase);
    __builtin_amdgcn_sched_barrier(0);
    consume<10>(cB, abase, lk16, axor, acc);
    __builtin_amdgcn_sched_barrier(0);
    loadc<14>(cB, wbase);
    __builtin_amdgcn_sched_barrier(0);
    consume<12>(cA, abase, lk16, axor, acc);
    consume<14>(cB, abase, lk16, axor, acc);

    __syncthreads();  // all reads of h(t-1) done; plds staged (vmcnt drained)

    // epilogue: h(t) = relu(acc + pre); only rows 0..7 are real sequences
    if (lk < 2) {
#pragma unroll
      for (int r = 0; r < 4; ++r) {
        int row = lk * 4 + r;
        int rxor = (row & 7) << 4;
#pragma unroll
        for (int ni = 0; ni < 4; ++ni) {
          int col = wid * 64 + ni * 16 + l15;
          float pvf = bf2f(*(const unsigned short*)(plds + (row * 512 + col) * 2));
          float v = fmaxf(acc[ni][r] + pvf, 0.f);
          *(short*)(hl + row * 1024 + ((col * 2) ^ rxor)) = (short)f2bf(v);
          if (!WRITE_OUTS && t == 31) hlast[(size_t)(n0 + row) * 512 + col] = v;
        }
      }
    }
    __syncthreads();  // h(t) visible to all
  }

  if (WRITE_OUTS) {
    short8 v = *(const short8*)(hl + wid * 1024 + ((lane * 16) ^ ((wid & 7) << 4)));
    *(short8*)(outs + ((size_t)31 * 2048 + n0 + wid) * 512 + lane * 8) = v;
  }
}

// ---------- head: s[b,n] = h_n.(wl-wg) + (sum_n h).wg + b_pred ----------
__global__ __launch_bounds__(512) void predict(
    const float* __restrict__ h1, const float* __restrict__ Wp,
    const float* __restrict__ bp, float* __restrict__ out) {
  const int b = blockIdx.x, tid = threadIdx.x;
  const int lane = tid & 63, wid = tid >> 6;
  __shared__ float red[8];
  __shared__ float sgd_s;
  const float* hb = h1 + (size_t)b * 256 * 512;
  float s = 0.f;
  for (int n = 0; n < 256; ++n) s += hb[(size_t)n * 512 + tid];
  float p = s * Wp[512 + tid];
#pragma unroll
  for (int o = 32; o; o >>= 1) p += __shfl_xor(p, o);
  if (lane == 0) red[wid] = p;
  __syncthreads();
  if (tid == 0) {
    float q = 0.f;
#pragma unroll
    for (int i = 0; i < 8; ++i) q += red[i];
    sgd_s = q;
  }
  __syncthreads();
  const float sgd = sgd_s + bp[0];
  float wd[8];
  const int k0 = lane * 8;
#pragma unroll
  for (int j = 0; j < 8; ++j) wd[j] = Wp[k0 + j] - Wp[512 + k0 + j];
  for (int c = 0; c < 32; ++c) {
    int n = wid * 32 + c;
    const float* hr = hb + (size_t)n * 512 + k0;
    float d = 0.f;
#pragma unroll
    for (int j = 0; j < 8; ++j) d += hr[j] * wd[j];
#pragma unroll
    for (int o = 1; o < 64; o <<= 1) d += __shfl_xor(d, o);
    if (lane == 0) out[b * 256 + n] = d + sgd;
  }
}

extern "C" void kernel_launch(void* const* d_in, const int* in_sizes, int n_in,
                              void* d_out, int out_size, void* d_ws, size_t ws_size,
                              hipStream_t stream) {
  const int* x = (const int*)d_in[0];
  const float* embed = (const float*)d_in[1];
  const float* Wih0 = (const float*)d_in[2];
  const float* Whh0 = (const float*)d_in[3];
  const float* bih0 = (const float*)d_in[4];
  const float* bhh0 = (const float*)d_in[5];
  const float* Wih1 = (const float*)d_in[6];
  const float* Whh1 = (const float*)d_in[7];
  const float* bih1 = (const float*)d_in[8];
  const float* bhh1 = (const float*)d_in[9];
  const float* Wpred = (const float*)d_in[10];
  const float* bpred = (const float*)d_in[11];
  float* out = (float*)d_out;

  char* ws = (char*)d_ws;
  short* whh0_bf = (short*)ws;                          // 512 KB
  short* whh1_bf = (short*)(ws + 524288);               // 512 KB
  short* wih0_bf = (short*)(ws + 1048576);              // 256 KB
  short* wih1_bf = (short*)(ws + 1310720);              // 512 KB
  short* pre     = (short*)(ws + 2097152);              // 64 MB (pre0, then pre1)
  short* outs0   = (short*)(ws + 2097152 + 67108864);   // 64 MB
  float* h1      = (float*)(ws + 2097152 + 2ll * 67108864);  // 4 MB

  prep_cvt<<<3584, 256, 0, stream>>>(Whh0, Whh1, Wih1, Wih0,
                                     whh0_bf, whh1_bf, wih1_bf, wih0_bf);
  gemm_pre<256, true><<<2048, 256, 0, stream>>>(embed, x, nullptr, wih0_bf, bih0, bhh0, pre);
  recur<true><<<256, 512, 0, stream>>>(pre, whh0_bf, outs0, nullptr);
  gemm_pre<512, false><<<2048, 256, 0, stream>>>(nullptr, nullptr, outs0, wih1_bf, bih1, bhh1, pre);
  recur<false><<<256, 512, 0, stream>>>(pre, whh1_bf, nullptr, h1);
  predict<<<8, 512, 0, stream>>>(h1, Wpred, bpred, out);
}

// Round 7
// 741.166 us; speedup vs baseline: 1.2249x; 1.2249x over previous
//
#include <hip/hip_runtime.h>
#include <hip/hip_bf16.h>

typedef __attribute__((ext_vector_type(4))) float f32x4;
typedef __attribute__((ext_vector_type(16))) float f32x16;
typedef __attribute__((ext_vector_type(8))) short short8;

#define DEVI __device__ __forceinline__

DEVI unsigned short f2bf(float x) {
  union { float f; unsigned u; } v; v.f = x;
  unsigned r = v.u + 0x7fffu + ((v.u >> 16) & 1u);
  return (unsigned short)(r >> 16);
}
DEVI float bf2f(unsigned short h) {
  union { unsigned u; float f; } v; v.u = ((unsigned)h) << 16;
  return v.f;
}
DEVI short8 pack8(f32x4 lo, f32x4 hi) {
  short8 r;
  r[0] = (short)f2bf(lo[0]); r[1] = (short)f2bf(lo[1]);
  r[2] = (short)f2bf(lo[2]); r[3] = (short)f2bf(lo[3]);
  r[4] = (short)f2bf(hi[0]); r[5] = (short)f2bf(hi[1]);
  r[6] = (short)f2bf(hi[2]); r[7] = (short)f2bf(hi[3]);
  return r;
}

DEVI void gld16(const void* g, void* l) {
  __builtin_amdgcn_global_load_lds(
      (const __attribute__((address_space(1))) void*)g,
      (__attribute__((address_space(3))) void*)l, 16, 0, 0);
}

// ---------- zero the cluster flags (both layers) ----------
__global__ __launch_bounds__(512) void zero_flags(unsigned* __restrict__ f) {
  f[threadIdx.x] = 0;
}

// ---------- prep: fp32 -> bf16 for W_hh0, W_hh1, W_ih1, W_ih0 ----------
__global__ __launch_bounds__(256) void prep_cvt(
    const float* __restrict__ whh0, const float* __restrict__ whh1,
    const float* __restrict__ wih1, const float* __restrict__ wih0,
    short* __restrict__ o_whh0, short* __restrict__ o_whh1,
    short* __restrict__ o_wih1, short* __restrict__ o_wih0) {
  int i = blockIdx.x * 256 + threadIdx.x;
  if (i < 262144) { o_whh0[i] = (short)f2bf(whh0[i]); return; }
  if (i < 524288) { int j = i - 262144; o_whh1[j] = (short)f2bf(whh1[j]); return; }
  if (i < 786432) { int j = i - 524288; o_wih1[j] = (short)f2bf(wih1[j]); return; }
  if (i < 917504) { int j = i - 786432; o_wih0[j] = (short)f2bf(wih0[j]); return; }
}

// ---------- GEMM: pre = A @ W^T + bias_a + bias_b  (bf16 out) ----------
template<int KDIM, bool GATHER>
__global__ __launch_bounds__(256) void gemm_pre(
    const float* __restrict__ embed, const int* __restrict__ xtok,
    const short* __restrict__ Abf, const short* __restrict__ Bbf,
    const float* __restrict__ bias_a, const float* __restrict__ bias_b,
    short* __restrict__ out) {
  __shared__ short smem[16384];          // As[128][64] @0, Bs[128][64] @8192 (shorts)
  short* As = smem;
  short* Bs = smem + 8192;

  const int tid = threadIdx.x;
  const int bM = (int)blockIdx.x >> 2;
  const int bN = (int)blockIdx.x & 3;
  const int m0 = bM * 128, n0 = bN * 128;

  f32x4 acc[4][4];
#pragma unroll
  for (int i = 0; i < 4; ++i)
#pragma unroll
    for (int j = 0; j < 4; ++j) acc[i][j] = (f32x4){0.f, 0.f, 0.f, 0.f};

  const int lane = tid & 63, wid = tid >> 6;
  const int wm = wid >> 1, wn = wid & 1;
  const int l15 = lane & 15, lk = lane >> 4;

  const int srow = tid >> 1;
  const int skh = (tid & 1) * 32;
  const int sxor = (srow & 7) << 4;
  const int sbyte0 = srow * 128 + skh * 2;

  const float* aG = nullptr;
  const short* aB = nullptr;
  if (GATHER) {
    int r = m0 + srow;
    int t = r >> 11, n = r & 2047;
    int tok = xtok[(n << 5) + t];
    aG = embed + (size_t)tok * 256;
  } else {
    aB = Abf + (size_t)(m0 + srow) * KDIM;
  }
  const short* bRow = Bbf + (size_t)(n0 + srow) * KDIM;

  for (int kb = 0; kb < KDIM; kb += 64) {
    __syncthreads();
#pragma unroll
    for (int c = 0; c < 4; ++c) {
      short8 pa;
      if (GATHER) {
        const float* src = aG + kb + skh + c * 8;
        f32x4 lo = *(const f32x4*)(src);
        f32x4 hi = *(const f32x4*)(src + 4);
        pa = pack8(lo, hi);
      } else {
        pa = *(const short8*)(aB + kb + skh + c * 8);
      }
      *(short8*)((char*)As + ((sbyte0 + c * 16) ^ sxor)) = pa;
      short8 pb = *(const short8*)(bRow + kb + skh + c * 8);
      *(short8*)((char*)Bs + ((sbyte0 + c * 16) ^ sxor)) = pb;
    }
    __syncthreads();
#pragma unroll
    for (int kt = 0; kt < 2; ++kt) {
      short8 av[4], bv[4];
#pragma unroll
      for (int mi = 0; mi < 4; ++mi) {
        int row = wm * 64 + mi * 16 + l15;
        int off = (row * 128 + kt * 64 + lk * 16) ^ ((row & 7) << 4);
        av[mi] = *(const short8*)((const char*)As + off);
      }
#pragma unroll
      for (int ni = 0; ni < 4; ++ni) {
        int col = wn * 64 + ni * 16 + l15;
        int off = (col * 128 + kt * 64 + lk * 16) ^ ((col & 7) << 4);
        bv[ni] = *(const short8*)((const char*)Bs + off);
      }
#pragma unroll
      for (int mi = 0; mi < 4; ++mi)
#pragma unroll
        for (int ni = 0; ni < 4; ++ni)
          acc[mi][ni] = __builtin_amdgcn_mfma_f32_16x16x32_bf16(av[mi], bv[ni], acc[mi][ni], 0, 0, 0);
    }
  }
  __syncthreads();
  float bsum[4];
#pragma unroll
  for (int ni = 0; ni < 4; ++ni) {
    int cg = n0 + wn * 64 + ni * 16 + l15;
    bsum[ni] = bias_a[cg] + bias_b[cg];
  }
  short* Cs = smem;
#pragma unroll
  for (int mi = 0; mi < 4; ++mi)
#pragma unroll
    for (int ni = 0; ni < 4; ++ni)
#pragma unroll
      for (int r = 0; r < 4; ++r) {
        int row = wm * 64 + mi * 16 + lk * 4 + r;
        int col = wn * 64 + ni * 16 + l15;
        Cs[row * 128 + col] = (short)f2bf(acc[mi][ni][r] + bsum[ni]);
      }
  __syncthreads();
  {
    int row = tid >> 1, colh = (tid & 1) * 64;
    size_t gbase = (size_t)(m0 + row) * 512 + n0 + colh;
#pragma unroll
    for (int c = 0; c < 8; ++c)
      *(short8*)(out + gbase + c * 8) = *(const short8*)&Cs[row * 128 + colh + c * 8];
  }
}

// ---------- clustered recurrence ----------
// 256 blocks = 64 seq-groups (g) x 4 col-parts (p). Block: 32 seqs, 128 W-rows
// fully LDS-resident (128 KB) + h[32][512] (32 KB) = 160 KB -> 1 block/CU, all
// resident. Per step: own-k MFMAs, spin on 3 peers' flags, pull their h slices
// from the mailbox (= outs buffer, per-t slots) via agent-scope loads, finish
// MFMAs, publish own h_t slice via agent-scope stores, vmcnt(0), flag = t+1.
// mbuf aliases pre (layer0): each block overwrites exactly the pv region it
// consumed this step; cross-block regions are disjoint -> safe at any skew.
template<bool HLAST>
__global__ __launch_bounds__(256) void recur_cl(
    const short* pre,                 // [32][2048][512] bf16 (aliases mbuf L0)
    const short* __restrict__ Wbf,    // [512][512] bf16
    unsigned* mbuf,                   // mailbox: [32][2048][512] bf16 as u32 pairs
    float* __restrict__ hlast,        // [2048][512] f32 (HLAST)
    unsigned* __restrict__ flags) {   // [64][4]
  __shared__ char Wl[131072];
  __shared__ char hlb[32768];
  const int tid = threadIdx.x;
  const int lane = tid & 63, w = tid >> 6;
  const int g = (int)blockIdx.x >> 2, p = (int)blockIdx.x & 3;
  const int seq0 = g * 32, col0 = p * 128;
  const int l31 = lane & 31, hi = lane >> 5;

  // stage W rows [col0, col0+128) once; source pre-XOR-swizzled so reads can
  // deswizzle (involution), LDS dest linear (gld16 constraint).
  {
    const short* wsb = Wbf + (size_t)col0 * 512;
#pragma unroll
    for (int i = 0; i < 32; ++i) {
      int wrow = w * 32 + i;
      gld16(wsb + (size_t)wrow * 512 + ((lane ^ (wrow & 15)) << 3),
            Wl + wrow * 1024);
    }
  }
  {
    short8 z = {0, 0, 0, 0, 0, 0, 0, 0};
#pragma unroll
    for (int i = 0; i < 8; ++i)
      *(short8*)(hlb + (i * 256 + tid) * 16) = z;
  }
  __syncthreads();

  const int myc = col0 + w * 32 + l31;  // this thread's output column
  const int wrow = w * 32 + l31;        // this thread's W LDS row

#pragma unroll 1
  for (int t = 0; t < 32; ++t) {
    f32x16 acc = {0.f, 0.f, 0.f, 0.f, 0.f, 0.f, 0.f, 0.f,
                  0.f, 0.f, 0.f, 0.f, 0.f, 0.f, 0.f, 0.f};
    // (a) own-k MFMAs: k in [col0, col0+128) — needs only own h slice
#pragma unroll
    for (int kk = 0; kk < 8; ++kk) {
      int c = (p * 8 + kk) * 2 + hi;
      short8 a = *(const short8*)(hlb + l31 * 1024 + ((c ^ (l31 & 15)) << 4));
      short8 b = *(const short8*)(Wl + wrow * 1024 + ((c ^ (wrow & 15)) << 4));
      acc = __builtin_amdgcn_mfma_f32_32x32x16_bf16(a, b, acc, 0, 0, 0);
    }
    // (b) wait for peers' h_{t-1}
    if (t > 0 && tid < 3) {
      int q = tid + (tid >= p);
      const unsigned* fp = flags + g * 4 + q;
      int guard = 0;
      while (__hip_atomic_load(fp, __ATOMIC_RELAXED, __HIP_MEMORY_SCOPE_AGENT) <
             (unsigned)t) {
        if (++guard > (1 << 20)) break;
      }
    }
    __syncthreads();  // B1: flags seen -> peer data globally visible
    // (c) pre values for this thread's outputs (consumed in epilogue)
    unsigned short pv[16];
    {
      const short* pb = pre + (size_t)t * (2048 * 512) + (size_t)seq0 * 512 + myc;
#pragma unroll
      for (int reg = 0; reg < 16; ++reg) {
        int row = (reg & 3) + 8 * (reg >> 2) + 4 * hi;
        pv[reg] = *(const unsigned short*)(pb + (size_t)row * 512);
      }
    }
    //     peer h_{t-1} slices: mailbox slot t-1 -> h LDS (agent loads bypass L2)
    if (t > 0) {
      const unsigned* mrow = mbuf + ((size_t)(t - 1) * 2048 + seq0) * 256;
#pragma unroll
      for (int i = 0; i < 24; ++i) {
        int idx = i * 256 + tid;            // 0..6143
        int qq = idx >> 11;                 // which of the 3 peers
        int q = qq + (qq >= p);
        int u = idx & 2047;                 // u32 index within 32x128 slice
        int row = u >> 6, cp = u & 63;      // colpair within peer's 128 cols
        unsigned v = __hip_atomic_load(mrow + (size_t)row * 256 + q * 64 + cp,
                                       __ATOMIC_RELAXED, __HIP_MEMORY_SCOPE_AGENT);
        int ch = (q * 16 + (cp >> 2)) ^ (row & 15);
        *(unsigned*)(hlb + row * 1024 + (ch << 4) + (cp & 3) * 4) = v;
      }
    }
    __syncthreads();  // B2: full h_{t-1} in LDS
    // (e) peer-k MFMAs
#pragma unroll
    for (int qq = 0; qq < 3; ++qq) {
      int q = qq + (qq >= p);
#pragma unroll
      for (int kk = 0; kk < 8; ++kk) {
        int c = (q * 8 + kk) * 2 + hi;
        short8 a = *(const short8*)(hlb + l31 * 1024 + ((c ^ (l31 & 15)) << 4));
        short8 b = *(const short8*)(Wl + wrow * 1024 + ((c ^ (wrow & 15)) << 4));
        acc = __builtin_amdgcn_mfma_f32_32x32x16_bf16(a, b, acc, 0, 0, 0);
      }
    }
    __syncthreads();  // B3: all reads of h_{t-1} complete
    // (g) epilogue: h_t = relu(acc + pre)
    unsigned short hv[16];
    float vf[16];
#pragma unroll
    for (int reg = 0; reg < 16; ++reg) {
      float v = fmaxf(acc[reg] + bf2f(pv[reg]), 0.f);
      vf[reg] = v;
      hv[reg] = f2bf(v);
    }
    // own slice -> h LDS (swizzled)
#pragma unroll
    for (int reg = 0; reg < 16; ++reg) {
      int row = (reg & 3) + 8 * (reg >> 2) + 4 * hi;
      *(unsigned short*)(hlb + row * 1024 +
                         ((((myc >> 3) ^ (row & 15)) << 4) + (myc & 7) * 2)) = hv[reg];
    }
    // publish to mailbox slot t (u32-packed via lane pairing, agent stores)
    {
      unsigned* d = mbuf + ((size_t)t * 2048 + seq0) * 256 + (myc >> 1);
#pragma unroll
      for (int reg = 0; reg < 16; ++reg) {
        unsigned mv = hv[reg];
        unsigned ov = (unsigned)__shfl_xor((int)mv, 1);
        if ((lane & 1) == 0) {
          int row = (reg & 3) + 8 * (reg >> 2) + 4 * hi;
          __hip_atomic_store(d + (size_t)row * 256, mv | (ov << 16),
                             __ATOMIC_RELAXED, __HIP_MEMORY_SCOPE_AGENT);
        }
      }
    }
    if (HLAST && t == 31) {
      float* dst = hlast + (size_t)seq0 * 512 + myc;
#pragma unroll
      for (int reg = 0; reg < 16; ++reg) {
        int row = (reg & 3) + 8 * (reg >> 2) + 4 * hi;
        dst[(size_t)row * 512] = vf[reg];
      }
    }
    asm volatile("s_waitcnt vmcnt(0)" ::: "memory");
    __syncthreads();  // B4: whole block's stores complete
    if (tid == 0)
      __hip_atomic_store(flags + g * 4 + p, (unsigned)(t + 1),
                         __ATOMIC_RELAXED, __HIP_MEMORY_SCOPE_AGENT);
  }
}

// ---------- head: s[b,n] = h_n.(wl-wg) + (sum_n h).wg + b_pred ----------
__global__ __launch_bounds__(512) void predict(
    const float* __restrict__ h1, const float* __restrict__ Wp,
    const float* __restrict__ bp, float* __restrict__ out) {
  const int b = blockIdx.x, tid = threadIdx.x;
  const int lane = tid & 63, wid = tid >> 6;
  __shared__ float red[8];
  __shared__ float sgd_s;
  const float* hb = h1 + (size_t)b * 256 * 512;
  float s = 0.f;
  for (int n = 0; n < 256; ++n) s += hb[(size_t)n * 512 + tid];
  float p = s * Wp[512 + tid];
#pragma unroll
  for (int o = 32; o; o >>= 1) p += __shfl_xor(p, o);
  if (lane == 0) red[wid] = p;
  __syncthreads();
  if (tid == 0) {
    float q = 0.f;
#pragma unroll
    for (int i = 0; i < 8; ++i) q += red[i];
    sgd_s = q;
  }
  __syncthreads();
  const float sgd = sgd_s + bp[0];
  float wd[8];
  const int k0 = lane * 8;
#pragma unroll
  for (int j = 0; j < 8; ++j) wd[j] = Wp[k0 + j] - Wp[512 + k0 + j];
  for (int c = 0; c < 32; ++c) {
    int n = wid * 32 + c;
    const float* hr = hb + (size_t)n * 512 + k0;
    float d = 0.f;
#pragma unroll
    for (int j = 0; j < 8; ++j) d += hr[j] * wd[j];
#pragma unroll
    for (int o = 1; o < 64; o <<= 1) d += __shfl_xor(d, o);
    if (lane == 0) out[b * 256 + n] = d + sgd;
  }
}

extern "C" void kernel_launch(void* const* d_in, const int* in_sizes, int n_in,
                              void* d_out, int out_size, void* d_ws, size_t ws_size,
                              hipStream_t stream) {
  const int* x = (const int*)d_in[0];
  const float* embed = (const float*)d_in[1];
  const float* Wih0 = (const float*)d_in[2];
  const float* Whh0 = (const float*)d_in[3];
  const float* bih0 = (const float*)d_in[4];
  const float* bhh0 = (const float*)d_in[5];
  const float* Wih1 = (const float*)d_in[6];
  const float* Whh1 = (const float*)d_in[7];
  const float* bih1 = (const float*)d_in[8];
  const float* bhh1 = (const float*)d_in[9];
  const float* Wpred = (const float*)d_in[10];
  const float* bpred = (const float*)d_in[11];
  float* out = (float*)d_out;

  char* ws = (char*)d_ws;
  short* whh0_bf = (short*)ws;                          // 512 KB
  short* whh1_bf = (short*)(ws + 524288);               // 512 KB
  short* wih0_bf = (short*)(ws + 1048576);              // 256 KB
  short* wih1_bf = (short*)(ws + 1310720);              // 512 KB
  unsigned* flags = (unsigned*)(ws + 1835008);          // 2 KB (in the gap)
  short* bufA    = (short*)(ws + 2097152);              // 64 MB: pre0 / h0-mailbox / GEMM_C A
  short* bufB    = (short*)(ws + 2097152 + 67108864);   // 64 MB: pre1
  float* h1      = (float*)(ws + 2097152 + 2ll * 67108864);  // 4 MB

  zero_flags<<<1, 512, 0, stream>>>(flags);
  prep_cvt<<<3584, 256, 0, stream>>>(Whh0, Whh1, Wih1, Wih0,
                                     whh0_bf, whh1_bf, wih1_bf, wih0_bf);
  gemm_pre<256, true><<<2048, 256, 0, stream>>>(embed, x, nullptr, wih0_bf, bih0, bhh0, bufA);
  // layer0: mailbox aliases pre (bufA); h_t lands in bufA[t] = GEMM_C's A.
  recur_cl<false><<<256, 256, 0, stream>>>(bufA, whh0_bf, (unsigned*)bufA, nullptr, flags);
  gemm_pre<512, false><<<2048, 256, 0, stream>>>(nullptr, nullptr, bufA, wih1_bf, bih1, bhh1, bufB);
  // layer1: pre = bufB; bufA (free now) serves as scratch mailbox.
  recur_cl<true><<<256, 256, 0, stream>>>(bufB, whh1_bf, (unsigned*)bufA, h1, flags + 256);
  predict<<<8, 512, 0, stream>>>(h1, Wpred, bpred, out);
}

// Round 8
// 464.407 us; speedup vs baseline: 1.9549x; 1.5959x over previous
//
#include <hip/hip_runtime.h>
#include <hip/hip_bf16.h>

typedef __attribute__((ext_vector_type(4))) float f32x4;
typedef __attribute__((ext_vector_type(8))) short short8;

#define DEVI __device__ __forceinline__

DEVI unsigned short f2bf(float x) {
  union { float f; unsigned u; } v; v.f = x;
  unsigned r = v.u + 0x7fffu + ((v.u >> 16) & 1u);
  return (unsigned short)(r >> 16);
}
DEVI float bf2f(unsigned short h) {
  union { unsigned u; float f; } v; v.u = ((unsigned)h) << 16;
  return v.f;
}
DEVI short8 pack8(f32x4 lo, f32x4 hi) {
  short8 r;
  r[0] = (short)f2bf(lo[0]); r[1] = (short)f2bf(lo[1]);
  r[2] = (short)f2bf(lo[2]); r[3] = (short)f2bf(lo[3]);
  r[4] = (short)f2bf(hi[0]); r[5] = (short)f2bf(hi[1]);
  r[6] = (short)f2bf(hi[2]); r[7] = (short)f2bf(hi[3]);
  return r;
}

DEVI void gld16(const void* g, void* l) {
  __builtin_amdgcn_global_load_lds(
      (const __attribute__((address_space(1))) void*)g,
      (__attribute__((address_space(3))) void*)l, 16, 0, 0);
}

// ---------- prep ----------
// whh0/whh1 -> bf16 in MFMA-fragment order:
//   element e: slot=e>>3, r=e&7; lane=slot&63, ni=(slot>>6)&3, wd=(slot>>8)&7,
//   kt=slot>>11; col=wd*64+ni*16+(lane&15); kr=kt*32+(lane>>4)*8+r;
//   dst[e] = bf16(W[col*512+kr])   => every 64-lane 16B gld16 is 1KB coalesced.
// wih0/wih1 -> plain bf16 (GEMM B operand).
__global__ __launch_bounds__(256) void prep_cvt(
    const float* __restrict__ whh0, const float* __restrict__ whh1,
    const float* __restrict__ wih1, const float* __restrict__ wih0,
    short* __restrict__ o_whh0fr, short* __restrict__ o_whh1fr,
    short* __restrict__ o_wih1, short* __restrict__ o_wih0) {
  int i = blockIdx.x * 256 + threadIdx.x;
  if (i < 524288) {
    const float* src = (i < 262144) ? whh0 : whh1;
    short* dst = (i < 262144) ? o_whh0fr : o_whh1fr;
    int e = i & 262143;
    int slot = e >> 3, r = e & 7;
    int lane = slot & 63, ni = (slot >> 6) & 3, wd = (slot >> 8) & 7, kt = slot >> 11;
    int col = wd * 64 + ni * 16 + (lane & 15);
    int kr = kt * 32 + (lane >> 4) * 8 + r;
    dst[e] = (short)f2bf(src[col * 512 + kr]);
    return;
  }
  if (i < 786432) { int j = i - 524288; o_wih1[j] = (short)f2bf(wih1[j]); return; }
  if (i < 917504) { int j = i - 786432; o_wih0[j] = (short)f2bf(wih0[j]); return; }
}

// ---------- GEMM: pre = A @ W^T + bias_a + bias_b  (bf16 out) ----------
template<int KDIM, bool GATHER>
__global__ __launch_bounds__(256) void gemm_pre(
    const float* __restrict__ embed, const int* __restrict__ xtok,
    const short* __restrict__ Abf, const short* __restrict__ Bbf,
    const float* __restrict__ bias_a, const float* __restrict__ bias_b,
    short* __restrict__ out) {
  __shared__ short smem[16384];          // As[128][64] @0, Bs[128][64] @8192 (shorts)
  short* As = smem;
  short* Bs = smem + 8192;

  const int tid = threadIdx.x;
  const int bM = (int)blockIdx.x >> 2;
  const int bN = (int)blockIdx.x & 3;
  const int m0 = bM * 128, n0 = bN * 128;

  f32x4 acc[4][4];
#pragma unroll
  for (int i = 0; i < 4; ++i)
#pragma unroll
    for (int j = 0; j < 4; ++j) acc[i][j] = (f32x4){0.f, 0.f, 0.f, 0.f};

  const int lane = tid & 63, wid = tid >> 6;
  const int wm = wid >> 1, wn = wid & 1;
  const int l15 = lane & 15, lk = lane >> 4;

  const int srow = tid >> 1;
  const int skh = (tid & 1) * 32;
  const int sxor = (srow & 7) << 4;
  const int sbyte0 = srow * 128 + skh * 2;

  const float* aG = nullptr;
  const short* aB = nullptr;
  if (GATHER) {
    int r = m0 + srow;
    int t = r >> 11, n = r & 2047;
    int tok = xtok[(n << 5) + t];
    aG = embed + (size_t)tok * 256;
  } else {
    aB = Abf + (size_t)(m0 + srow) * KDIM;
  }
  const short* bRow = Bbf + (size_t)(n0 + srow) * KDIM;

  for (int kb = 0; kb < KDIM; kb += 64) {
    __syncthreads();
#pragma unroll
    for (int c = 0; c < 4; ++c) {
      short8 pa;
      if (GATHER) {
        const float* src = aG + kb + skh + c * 8;
        f32x4 lo = *(const f32x4*)(src);
        f32x4 hi = *(const f32x4*)(src + 4);
        pa = pack8(lo, hi);
      } else {
        pa = *(const short8*)(aB + kb + skh + c * 8);
      }
      *(short8*)((char*)As + ((sbyte0 + c * 16) ^ sxor)) = pa;
      short8 pb = *(const short8*)(bRow + kb + skh + c * 8);
      *(short8*)((char*)Bs + ((sbyte0 + c * 16) ^ sxor)) = pb;
    }
    __syncthreads();
#pragma unroll
    for (int kt = 0; kt < 2; ++kt) {
      short8 av[4], bv[4];
#pragma unroll
      for (int mi = 0; mi < 4; ++mi) {
        int row = wm * 64 + mi * 16 + l15;
        int off = (row * 128 + kt * 64 + lk * 16) ^ ((row & 7) << 4);
        av[mi] = *(const short8*)((const char*)As + off);
      }
#pragma unroll
      for (int ni = 0; ni < 4; ++ni) {
        int col = wn * 64 + ni * 16 + l15;
        int off = (col * 128 + kt * 64 + lk * 16) ^ ((col & 7) << 4);
        bv[ni] = *(const short8*)((const char*)Bs + off);
      }
#pragma unroll
      for (int mi = 0; mi < 4; ++mi)
#pragma unroll
        for (int ni = 0; ni < 4; ++ni)
          acc[mi][ni] = __builtin_amdgcn_mfma_f32_16x16x32_bf16(av[mi], bv[ni], acc[mi][ni], 0, 0, 0);
    }
  }
  __syncthreads();
  float bsum[4];
#pragma unroll
  for (int ni = 0; ni < 4; ++ni) {
    int cg = n0 + wn * 64 + ni * 16 + l15;
    bsum[ni] = bias_a[cg] + bias_b[cg];
  }
  short* Cs = smem;
#pragma unroll
  for (int mi = 0; mi < 4; ++mi)
#pragma unroll
    for (int ni = 0; ni < 4; ++ni)
#pragma unroll
      for (int r = 0; r < 4; ++r) {
        int row = wm * 64 + mi * 16 + lk * 4 + r;
        int col = wn * 64 + ni * 16 + l15;
        Cs[row * 128 + col] = (short)f2bf(acc[mi][ni][r] + bsum[ni]);
      }
  __syncthreads();
  {
    int row = tid >> 1, colh = (tid & 1) * 64;
    size_t gbase = (size_t)(m0 + row) * 512 + n0 + colh;
#pragma unroll
    for (int c = 0; c < 8; ++c)
      *(short8*)(out + gbase + c * 8) = *(const short8*)&Cs[row * 128 + colh + c * 8];
  }
}

// ---------- recurrence: h_t = relu(pre_t + h_{t-1} @ W_hh^T) ----------
// 128 blocks x 512 threads. LDS 160 KB -> 1 block/CU (structural).
// W (frag-order) : kt0-1 LDS-stationary (64 KB, staged once); kt2-15 stream
// from L2 through per-wave 2-slot LDS rings via gld16 (flow-through; data
// never in VGPRs). Counted vmcnt ring (per-thread, in-order retire):
//   per step issue order: P(2 plds gld16) ; j=0..13 { consume slot j&1 ;
//   refill it (4 gld16) }. Before consuming: j=0 outstanding={P}=2;
//   j=1 {P,S0r}=6; j>=2 {P?,r(j-2),r(j-1)} -> wait vmcnt(4) retires r(j-2).
//   __syncthreads (B1) drains vmcnt(0) (compiler-guaranteed) -> counts reset.
template<bool WRITE_OUTS>
__global__ __launch_bounds__(512) void recur(
    const short* __restrict__ pre,   // [32][2048][512] bf16
    const short* __restrict__ wfr,   // W_hh in fragment order (see prep)
    short* __restrict__ outs,        // [32][2048][512] bf16 (WRITE_OUTS)
    float* __restrict__ hlast) {     // [2048][512] f32 (!WRITE_OUTS)
  __shared__ __align__(16) char lds[163840];
  char* Wst  = lds;            // 64 KB: [wid][kt0..1][ni][lane]16B
  char* ring = lds + 65536;    // 64 KB: [wid][slot0..1][ni][lane]16B
  char* hl   = lds + 131072;   // 16 KB: h tile 16x512 bf16, XOR-swizzled
  char* plds = lds + 147456;   // 16 KB: pre tile 16x512 bf16, linear
  const int tid = threadIdx.x;
  const int lane = tid & 63, wid = tid >> 6;
  const int l15 = lane & 15, lk = lane >> 4;
  const int n0 = (int)blockIdx.x * 16;

  const short* wsl = wfr + wid * 2048 + lane * 8;  // per-lane frag source base
  char* wstw = Wst + wid * 8192;
  char* ringw = ring + wid * 8192;

  // prologue: stationary kt0,kt1 (8 gld16) then ring kt2->S0, kt3->S1 (8)
#pragma unroll
  for (int kt = 0; kt < 2; ++kt)
#pragma unroll
    for (int ni = 0; ni < 4; ++ni)
      gld16(wsl + kt * 16384 + ni * 512, wstw + (kt * 4 + ni) * 1024);
#pragma unroll
  for (int s = 0; s < 2; ++s)
#pragma unroll
    for (int ni = 0; ni < 4; ++ni)
      gld16(wsl + (2 + s) * 16384 + ni * 512, ringw + s * 4096 + ni * 1024);

  {  // zero h(-1)
    short8 z = {0, 0, 0, 0, 0, 0, 0, 0};
    *(short8*)(hl + tid * 32) = z;
    *(short8*)(hl + tid * 32 + 16) = z;
  }
  __syncthreads();

  const int axor = (l15 & 7) << 4;
  const char* abase = hl + l15 * 1024;
  const int crow = tid >> 5, cseg = tid & 31;
  const int cxor = (crow & 7) << 4;

#pragma unroll 1
  for (int t = 0; t < 32; ++t) {
    // P: stage pre rows 2*wid, 2*wid+1 (consumed after B1)
    {
      const short* psrc = pre + ((size_t)t * 2048 + n0) * 512;
      gld16(psrc + wid * 1024 + lane * 8, plds + wid * 2048);
      gld16(psrc + wid * 1024 + 512 + lane * 8, plds + wid * 2048 + 1024);
    }

    f32x4 acc[4];
#pragma unroll
    for (int ni = 0; ni < 4; ++ni) acc[ni] = (f32x4){0.f, 0.f, 0.f, 0.f};

    // stationary kt0,kt1 (wait retires the 8 prologue staging loads at t=0)
    asm volatile("s_waitcnt vmcnt(10)" ::: "memory");
#pragma unroll
    for (int kt = 0; kt < 2; ++kt) {
      short8 a = *(const short8*)(abase + ((kt * 64 + lk * 16) ^ axor));
#pragma unroll
      for (int ni = 0; ni < 4; ++ni) {
        short8 b = *(const short8*)(wstw + (kt * 4 + ni) * 1024 + lane * 16);
        acc[ni] = __builtin_amdgcn_mfma_f32_16x16x32_bf16(a, b, acc[ni], 0, 0, 0);
      }
    }

    // streamed kt2..15 through the 2-slot ring
#pragma unroll
    for (int j = 0; j < 14; ++j) {
      const int kt = 2 + j;
      char* slot = ringw + (j & 1) * 4096;
      if (j < 2) { asm volatile("s_waitcnt vmcnt(6)" ::: "memory"); }
      else       { asm volatile("s_waitcnt vmcnt(4)" ::: "memory"); }
      short8 a  = *(const short8*)(abase + ((kt * 64 + lk * 16) ^ axor));
      short8 b0 = *(const short8*)(slot + lane * 16);
      short8 b1 = *(const short8*)(slot + 1024 + lane * 16);
      short8 b2 = *(const short8*)(slot + 2048 + lane * 16);
      short8 b3 = *(const short8*)(slot + 3072 + lane * 16);
      acc[0] = __builtin_amdgcn_mfma_f32_16x16x32_bf16(a, b0, acc[0], 0, 0, 0);
      acc[1] = __builtin_amdgcn_mfma_f32_16x16x32_bf16(a, b1, acc[1], 0, 0, 0);
      acc[2] = __builtin_amdgcn_mfma_f32_16x16x32_bf16(a, b2, acc[2], 0, 0, 0);
      acc[3] = __builtin_amdgcn_mfma_f32_16x16x32_bf16(a, b3, acc[3], 0, 0, 0);
      // refill this slot: kt+2 (j<12) or next step's kt2/kt3 (j>=12)
      const int ktr = (j < 12) ? (kt + 2) : (kt - 12);
      const short* rs = wsl + ktr * 16384;
#pragma unroll
      for (int ni = 0; ni < 4; ++ni)
        gld16(rs + ni * 512, slot + ni * 1024);
    }

    // stream h(t-1) to outs (reads hl; must precede B1/epilogue)
    if (WRITE_OUTS && t > 0) {
      short8 v0 = *(const short8*)(hl + crow * 1024 + ((cseg * 32) ^ cxor));
      short8 v1 = *(const short8*)(hl + crow * 1024 + ((cseg * 32 + 16) ^ cxor));
      short* dst = outs + ((size_t)(t - 1) * 2048 + n0 + crow) * 512 + cseg * 16;
      *(short8*)dst = v0;
      *(short8*)(dst + 8) = v1;
    }

    __syncthreads();  // B1: drains vmcnt(0) -> plds/ring staged; h reads done

    // epilogue: h(t) = relu(acc + pre) in place (XOR-swizzled)
#pragma unroll
    for (int r = 0; r < 4; ++r) {
      int row = lk * 4 + r;
      int rxor = (row & 7) << 4;
#pragma unroll
      for (int ni = 0; ni < 4; ++ni) {
        int col = wid * 64 + ni * 16 + l15;
        float pvf = bf2f(*(const unsigned short*)(plds + row * 1024 + col * 2));
        float v = fmaxf(acc[ni][r] + pvf, 0.f);
        *(short*)(hl + row * 1024 + ((col * 2) ^ rxor)) = (short)f2bf(v);
        if (!WRITE_OUTS && t == 31) hlast[(size_t)(n0 + row) * 512 + col] = v;
      }
    }
    __syncthreads();  // B2: h(t) visible to all
  }

  if (WRITE_OUTS) {
    short8 v0 = *(const short8*)(hl + crow * 1024 + ((cseg * 32) ^ cxor));
    short8 v1 = *(const short8*)(hl + crow * 1024 + ((cseg * 32 + 16) ^ cxor));
    short* dst = outs + ((size_t)31 * 2048 + n0 + crow) * 512 + cseg * 16;
    *(short8*)dst = v0;
    *(short8*)(dst + 8) = v1;
  }
}

// ---------- head: s[b,n] = h_n.(wl-wg) + (sum_n h).wg + b_pred ----------
__global__ __launch_bounds__(512) void predict(
    const float* __restrict__ h1, const float* __restrict__ Wp,
    const float* __restrict__ bp, float* __restrict__ out) {
  const int b = blockIdx.x, tid = threadIdx.x;
  const int lane = tid & 63, wid = tid >> 6;
  __shared__ float red[8];
  __shared__ float sgd_s;
  const float* hb = h1 + (size_t)b * 256 * 512;
  float s = 0.f;
  for (int n = 0; n < 256; ++n) s += hb[(size_t)n * 512 + tid];
  float p = s * Wp[512 + tid];
#pragma unroll
  for (int o = 32; o; o >>= 1) p += __shfl_xor(p, o);
  if (lane == 0) red[wid] = p;
  __syncthreads();
  if (tid == 0) {
    float q = 0.f;
#pragma unroll
    for (int i = 0; i < 8; ++i) q += red[i];
    sgd_s = q;
  }
  __syncthreads();
  const float sgd = sgd_s + bp[0];
  float wd[8];
  const int k0 = lane * 8;
#pragma unroll
  for (int j = 0; j < 8; ++j) wd[j] = Wp[k0 + j] - Wp[512 + k0 + j];
  for (int c = 0; c < 32; ++c) {
    int n = wid * 32 + c;
    const float* hr = hb + (size_t)n * 512 + k0;
    float d = 0.f;
#pragma unroll
    for (int j = 0; j < 8; ++j) d += hr[j] * wd[j];
#pragma unroll
    for (int o = 1; o < 64; o <<= 1) d += __shfl_xor(d, o);
    if (lane == 0) out[b * 256 + n] = d + sgd;
  }
}

extern "C" void kernel_launch(void* const* d_in, const int* in_sizes, int n_in,
                              void* d_out, int out_size, void* d_ws, size_t ws_size,
                              hipStream_t stream) {
  const int* x = (const int*)d_in[0];
  const float* embed = (const float*)d_in[1];
  const float* Wih0 = (const float*)d_in[2];
  const float* Whh0 = (const float*)d_in[3];
  const float* bih0 = (const float*)d_in[4];
  const float* bhh0 = (const float*)d_in[5];
  const float* Wih1 = (const float*)d_in[6];
  const float* Whh1 = (const float*)d_in[7];
  const float* bih1 = (const float*)d_in[8];
  const float* bhh1 = (const float*)d_in[9];
  const float* Wpred = (const float*)d_in[10];
  const float* bpred = (const float*)d_in[11];
  float* out = (float*)d_out;

  char* ws = (char*)d_ws;
  short* whh0_fr = (short*)ws;                          // 512 KB (frag order)
  short* whh1_fr = (short*)(ws + 524288);               // 512 KB (frag order)
  short* wih0_bf = (short*)(ws + 1048576);              // 256 KB
  short* wih1_bf = (short*)(ws + 1310720);              // 512 KB
  short* pre     = (short*)(ws + 2097152);              // 64 MB (pre0, then pre1)
  short* outs0   = (short*)(ws + 2097152 + 67108864);   // 64 MB
  float* h1      = (float*)(ws + 2097152 + 2ll * 67108864);  // 4 MB

  prep_cvt<<<3584, 256, 0, stream>>>(Whh0, Whh1, Wih1, Wih0,
                                     whh0_fr, whh1_fr, wih1_bf, wih0_bf);
  gemm_pre<256, true><<<2048, 256, 0, stream>>>(embed, x, nullptr, wih0_bf, bih0, bhh0, pre);
  recur<true><<<128, 512, 0, stream>>>(pre, whh0_fr, outs0, nullptr);
  gemm_pre<512, false><<<2048, 256, 0, stream>>>(nullptr, nullptr, outs0, wih1_bf, bih1, bhh1, pre);
  recur<false><<<128, 512, 0, stream>>>(pre, whh1_fr, nullptr, h1);
  predict<<<8, 512, 0, stream>>>(h1, Wpred, bpred, out);
}